// Round 1
// baseline (228.175 us; speedup 1.0000x reference)
//
#include <hip/hip_runtime.h>

#define C_DIM 128
#define H_DIM 32

// fast tanh: tanh(x) = 1 - 2/(e^{2x}+1). Handles +-inf correctly
// (x>>0: e=inf -> rcp=0 -> 1; x<<0: e=0 -> 1-2 = -1).
__device__ __forceinline__ float tanh_fast(float x) {
    float e = __expf(2.0f * x);
    return 1.0f - 2.0f * __builtin_amdgcn_rcpf(e + 1.0f);
}

// Chebyshev -> monomial transform of coeffs, done once per launch.
// T0=1, T1=t, T2=2t^2-1, T3=4t^3-3t, T4=8t^4-8t^2+1
//   p(t) = e0 + e1 t + e2 t^2 + e3 t^3 + e4 t^4
//   e0 = c0 - c2 + c4; e1 = c1 - 3c3; e2 = 2c2 - 8c4; e3 = 4c3; e4 = 8c4
// e0 is folded into a per-output bias (sum over input channels).
__global__ void prep_kernel(const float* __restrict__ c1, const float* __restrict__ c2,
                            float* __restrict__ E1, float* __restrict__ bias1,
                            float* __restrict__ E2, float* __restrict__ bias2) {
    int tid = threadIdx.x;
    // E1[i*H+o] = {e1,e2,e3,e4} for layer 1
    for (int p = tid; p < C_DIM * H_DIM; p += 256) {
        const float* c = c1 + p * 5;
        float4 e;
        e.x = c[1] - 3.0f * c[3];
        e.y = 2.0f * c[2] - 8.0f * c[4];
        e.z = 4.0f * c[3];
        e.w = 8.0f * c[4];
        reinterpret_cast<float4*>(E1)[p] = e;
    }
    if (tid < H_DIM) {
        // bias1[o] = sum_i e0[i,o]
        float b = 0.0f;
        for (int i = 0; i < C_DIM; ++i) {
            const float* c = c1 + (i * H_DIM + tid) * 5;
            b += c[0] - c[2] + c[4];
        }
        bias1[tid] = b;
        // layer-2 monomial coeffs
        const float* c = c2 + tid * 5;
        float4 e;
        e.x = c[1] - 3.0f * c[3];
        e.y = 2.0f * c[2] - 8.0f * c[4];
        e.z = 4.0f * c[3];
        e.w = 8.0f * c[4];
        reinterpret_cast<float4*>(E2)[tid] = e;
    }
    __shared__ float s[H_DIM];
    if (tid < H_DIM) {
        const float* c = c2 + tid * 5;
        s[tid] = c[0] - c[2] + c[4];
    }
    __syncthreads();
    if (tid == 0) {
        float b = 0.0f;
        for (int h = 0; h < H_DIM; ++h) b += s[h];
        bias2[0] = b;
    }
}

__global__ __launch_bounds__(256) void fused_kernel(
        const float* __restrict__ PRV, const float* __restrict__ PR,
        const float* __restrict__ E1, const float* __restrict__ bias1,
        const float* __restrict__ E2, const float* __restrict__ bias2,
        const float* __restrict__ gamma, const float* __restrict__ beta,
        const float* __restrict__ alphap, float* __restrict__ out) {
    const int tid = threadIdx.x;
    const int row = blockIdx.x * 256 + tid;

    float acc[H_DIM];
    #pragma unroll
    for (int o = 0; o < H_DIM; ++o) acc[o] = bias1[o];  // uniform -> s_load

    // ---- layer 1: context[o] = bias1[o] + sum_i sum_k e_k[i,o] * t_i^k ----
    const float4* pr4 = reinterpret_cast<const float4*>(PR) + (size_t)row * (C_DIM / 4);
    #pragma unroll 1
    for (int ii = 0; ii < C_DIM / 4; ++ii) {
        float4 p = pr4[ii];
        float xs[4] = {p.x, p.y, p.z, p.w};
        #pragma unroll
        for (int e = 0; e < 4; ++e) {
            float t  = tanh_fast(xs[e]);
            float t2 = t * t;
            float t3 = t2 * t;
            float t4 = t2 * t2;
            const float4* Ei = reinterpret_cast<const float4*>(E1) + (ii * 4 + e) * H_DIM;
            #pragma unroll
            for (int o = 0; o < H_DIM; ++o) {
                float4 cx = Ei[o];  // uniform address -> scalar load
                float a = acc[o];
                a = fmaf(cx.x, t,  a);
                a = fmaf(cx.y, t2, a);
                a = fmaf(cx.z, t3, a);
                a = fmaf(cx.w, t4, a);
                acc[o] = a;
            }
        }
    }

    // ---- LayerNorm over H, then ReLU + layer-2 ChebyKAN -> sigmoid ----
    float mu = 0.0f;
    #pragma unroll
    for (int o = 0; o < H_DIM; ++o) mu += acc[o];
    mu *= (1.0f / H_DIM);
    float var = 0.0f;
    #pragma unroll
    for (int o = 0; o < H_DIM; ++o) {
        float d = acc[o] - mu;
        var = fmaf(d, d, var);
    }
    var *= (1.0f / H_DIM);
    float rs = rsqrtf(var + 1e-5f);

    float z = bias2[0];
    #pragma unroll
    for (int o = 0; o < H_DIM; ++o) {
        float h = fmaf((acc[o] - mu) * rs, gamma[o], beta[o]);
        h = fmaxf(h, 0.0f);
        float t  = tanh_fast(h);
        float t2 = t * t;
        float t3 = t2 * t;
        float t4 = t2 * t2;
        float4 cx = reinterpret_cast<const float4*>(E2)[o];
        z = fmaf(cx.x, t,  z);
        z = fmaf(cx.y, t2, z);
        z = fmaf(cx.z, t3, z);
        z = fmaf(cx.w, t4, z);
    }
    float attn  = __builtin_amdgcn_rcpf(1.0f + __expf(-z));
    float scale = fmaf(alphap[0], attn, 1.0f);

    // ---- coalesced output sweep: out = PRV * (1 + alpha*attn) ----
    __shared__ float s_scale[256];
    s_scale[tid] = scale;
    __syncthreads();

    const size_t base = (size_t)blockIdx.x * 256 * (C_DIM / 4);
    const float4* prv4 = reinterpret_cast<const float4*>(PRV) + base;
    float4* out4 = reinterpret_cast<float4*>(out) + base;
    #pragma unroll 1
    for (int it = 0; it < C_DIM / 4; ++it) {
        int idx = it * 256 + tid;
        float sc = s_scale[idx >> 5];  // 32 float4 per row
        float4 v = prv4[idx];
        v.x *= sc; v.y *= sc; v.z *= sc; v.w *= sc;
        out4[idx] = v;
    }
}

extern "C" void kernel_launch(void* const* d_in, const int* in_sizes, int n_in,
                              void* d_out, int out_size, void* d_ws, size_t ws_size,
                              hipStream_t stream) {
    const float* PRV    = (const float*)d_in[0];
    const float* PR     = (const float*)d_in[1];
    const float* c1     = (const float*)d_in[2];
    const float* gamma  = (const float*)d_in[3];
    const float* beta   = (const float*)d_in[4];
    const float* c2     = (const float*)d_in[5];
    const float* alphap = (const float*)d_in[6];
    float* out = (float*)d_out;

    float* ws    = (float*)d_ws;
    float* E1    = ws;            // 128*32*4 = 16384 floats
    float* bias1 = ws + 16384;    // 32
    float* E2    = ws + 16416;    // 32*4 = 128
    float* bias2 = ws + 16544;    // 1

    const int N = in_sizes[0] / C_DIM;

    hipLaunchKernelGGL(prep_kernel, dim3(1), dim3(256), 0, stream,
                       c1, c2, E1, bias1, E2, bias2);
    hipLaunchKernelGGL(fused_kernel, dim3(N / 256), dim3(256), 0, stream,
                       PRV, PR, E1, bias1, E2, bias2, gamma, beta, alphap, out);
}